// Round 1
// 268.137 us; speedup vs baseline: 1.0015x; 1.0015x over previous
//
#include <hip/hip_runtime.h>

// GPT2 grouped-query attention, bf16 MFMA pipeline, round 8.
// R8: qkv_gemm moved to 256x256 8-phase schedule (T2+T3+T4+T5): BK=64,
// 8 waves, 128KB dbuf LDS, counted vmcnt(4) per K-tile (never 0 in loop),
// xor-swizzled ds_read via pre-swizzled global_load_lds source.
// ws (u16 elems): q_att[8M] | k_att[8M] | v_t[8M] | Xb/ctx[8M] | Wcat[3M] | Wob[1M]

typedef __attribute__((ext_vector_type(8))) short short8;
typedef __attribute__((ext_vector_type(4))) float f32x4;
typedef unsigned int u32;
typedef unsigned short u16;

#define MFMA16(a, b, c) __builtin_amdgcn_mfma_f32_16x16x32_bf16((a), (b), (c), 0, 0, 0)

union S8 { short8 s; uint2 v[2]; u32 u[4]; };

__device__ __forceinline__ u32 f2bf1(float x) {
    union { float f; u32 u; } v; v.f = x;
    return (v.u + 0x7fffu + ((v.u >> 16) & 1u)) >> 16;   // RNE
}

__device__ __forceinline__ void gld16(u16* lds, const u16* g) {
    __builtin_amdgcn_global_load_lds(
        (const __attribute__((address_space(1))) unsigned int*)(g),
        (__attribute__((address_space(3))) unsigned int*)(lds),
        16, 0, 0);
}

// ---------------------------------------------------------------------------
// Kernel 0: fp32 -> bf16 convert.
// ---------------------------------------------------------------------------
__global__ __launch_bounds__(256) void convert(
    const float* __restrict__ X, const float* __restrict__ Wq,
    const float* __restrict__ Wk, const float* __restrict__ Wv,
    const float* __restrict__ Wo,
    u16* __restrict__ Xb, u16* __restrict__ Wcat, u16* __restrict__ Wob)
{
    const size_t M8 = 8388608, M1 = 1048576;
    size_t i = ((size_t)blockIdx.x * 256 + threadIdx.x) * 16;
    const float* src; u16* dst;
    if (i < M8)              { src = X  + i;                dst = Xb   + i; }
    else if (i < M8 + M1)    { src = Wq + (i - M8);         dst = Wcat + (i - M8); }
    else if (i < M8 + 2*M1)  { src = Wk + (i - M8 - M1);    dst = Wcat + (i - M8); }
    else if (i < M8 + 3*M1)  { src = Wv + (i - M8 - 2*M1);  dst = Wcat + (i - M8); }
    else                     { src = Wo + (i - M8 - 3*M1);  dst = Wob  + (i - M8 - 3*M1); }
#pragma unroll
    for (int j = 0; j < 2; ++j) {
        float4 a = ((const float4*)src)[2 * j];
        float4 b = ((const float4*)src)[2 * j + 1];
        uint4 o;
        o.x = f2bf1(a.x) | (f2bf1(a.y) << 16);
        o.y = f2bf1(a.z) | (f2bf1(a.w) << 16);
        o.z = f2bf1(b.x) | (f2bf1(b.y) << 16);
        o.w = f2bf1(b.z) | (f2bf1(b.w) << 16);
        ((uint4*)dst)[j] = o;
    }
}

// ---------------------------------------------------------------------------
// Kernel 1: fused QKV GEMM, 256x256 8-phase. C[8192][3072] = Xb @ Wcat^T.
// 8 waves (2M x 4N), per-wave 128x64 output, BK=64, 2 K-tiles per 8 phases.
// LDS: [parity][A0,A1,B0,B1][128*64] u16 = 128 KB.
// Staging schedule (tile t): ph0 A1(t+1), ph1 B0(t+1), ph2 A0(t+2),
// ph3 B1(t+2); vmcnt(4) at end of tile (drains everything through t+1).
// Region safety: each region's last reader drains (lgkmcnt(0) pre-MFMA)
// >=1 barrier before its DMA re-issue; verified per-half against schedule.
// ---------------------------------------------------------------------------
__global__ __launch_bounds__(512) void qkv_gemm8(
    const u16* __restrict__ Xb, const u16* __restrict__ Wcat,
    const float* __restrict__ b0, const float* __restrict__ b1,
    const float* __restrict__ b2,
    u16* __restrict__ q_att, u16* __restrict__ k_att, u16* __restrict__ v_t)
{
    const int nb = blockIdx.x, mb = blockIdx.y;
    const int mat = nb >> 2;                      // 4 nb-tiles per matrix

    __shared__ __align__(16) u16 lds[2][4][8192]; // 128 KB
    u16* ldsf = &lds[0][0][0];

    const int t = threadIdx.x, wave = t >> 6, lane = t & 63;
    const int l15 = lane & 15, quad = lane >> 4;
    const int wr = wave >> 2, wc = wave & 3;      // 2M x 4N wave grid

    const u16* Ab = Xb   + (size_t)(mb * 256) * 1024;
    const u16* Bb = Wcat + (size_t)(nb * 256) * 1024;

    // staging source offsets (u16), pre-swizzled: col ^= (row&7)<<3
    int offs[2][2];
#pragma unroll
    for (int h = 0; h < 2; ++h)
#pragma unroll
        for (int j = 0; j < 2; ++j) {
            int rl = j * 64 + wave * 8 + (lane >> 3);          // row in half
            int cs = ((lane & 7) ^ (lane >> 3)) << 3;          // swizzled col
            offs[h][j] = (h * 128 + rl) * 1024 + cs;
        }

    // fragment-read columns with matching swizzle (row&7 == l15&7 always)
    const int swz = (l15 & 7) << 3;
    const int c0 = (quad * 8) ^ swz;              // ks=0
    const int c1 = (32 + quad * 8) ^ swz;         // ks=1
    const int rb0 = (wc & 1) * 64;                // B row base within half

#define STAGE(reg, tt) do {                                                   \
        u16* lb_ = ldsf + (((tt) & 1) * 32768) + (reg) * 8192;                \
        const u16* gb_ = (((reg) < 2) ? Ab : Bb) + (size_t)(tt) * 64;         \
        const int h_ = (reg) & 1;                                             \
        gld16(lb_ + wave * 512,       gb_ + offs[h_][0]);                     \
        gld16(lb_ + (8 + wave) * 512, gb_ + offs[h_][1]);                     \
    } while (0)

#define LDA4(MH) _Pragma("unroll")                                            \
    for (int mt = 0; mt < 4; ++mt) {                                          \
        const u16* ra_ = LA + ((MH) * 64 + mt * 16 + l15) * 64;               \
        af[mt][0] = *(const short8*)(ra_ + c0);                               \
        af[mt][1] = *(const short8*)(ra_ + c1);                               \
    }

#define LDB2(NT0) _Pragma("unroll")                                           \
    for (int nt = 0; nt < 2; ++nt) {                                          \
        const u16* rb_ = LB + (rb0 + ((NT0) + nt) * 16 + l15) * 64;           \
        bf[(NT0) + nt][0] = *(const short8*)(rb_ + c0);                       \
        bf[(NT0) + nt][1] = *(const short8*)(rb_ + c1);                       \
    }

#define MMAQ(MT0, NT0) _Pragma("unroll")                                      \
    for (int mt = 0; mt < 4; ++mt) _Pragma("unroll")                          \
        for (int nt = 0; nt < 2; ++nt) {                                      \
            acc[(MT0)+mt][(NT0)+nt] =                                         \
                MFMA16(af[mt][0], bf[(NT0)+nt][0], acc[(MT0)+mt][(NT0)+nt]);  \
            acc[(MT0)+mt][(NT0)+nt] =                                         \
                MFMA16(af[mt][1], bf[(NT0)+nt][1], acc[(MT0)+mt][(NT0)+nt]);  \
        }

#define PHASE_TAIL()                                                          \
    __builtin_amdgcn_s_barrier();                                             \
    asm volatile("s_waitcnt lgkmcnt(0)" ::: "memory");                        \
    __builtin_amdgcn_s_setprio(1);

#define PHASE_END()                                                           \
    __builtin_amdgcn_s_setprio(0);                                            \
    __builtin_amdgcn_s_barrier();

    f32x4 acc[8][4] = {};
    short8 af[4][2], bf[4][2];

    // prologue: tile0 full + A0(1), B1(1); keep the newest 2 half-tiles
    // (4 loads) in flight.
    STAGE(0, 0); STAGE(2, 0); STAGE(1, 0); STAGE(3, 0);
    STAGE(0, 1); STAGE(3, 1);
    asm volatile("s_waitcnt vmcnt(4)" ::: "memory");
    __builtin_amdgcn_s_barrier();

#pragma unroll 2
    for (int tt = 0; tt < 16; ++tt) {
        const int p = tt & 1;
        const u16* LA = ldsf + p * 32768 + wr * 8192;
        const u16* LB = ldsf + p * 32768 + (2 + (wc >> 1)) * 8192;

        // PH0: quadrant (M0,N0); 12 ds_reads; stage A1(t+1)
        LDA4(0); LDB2(0);
        if (tt + 1 < 16) STAGE(1, tt + 1);
        PHASE_TAIL(); MMAQ(0, 0); PHASE_END();

        // PH1: (M0,N1); 4 ds_reads; stage B0(t+1)
        LDB2(2);
        if (tt + 1 < 16) STAGE(2, tt + 1);
        PHASE_TAIL(); MMAQ(0, 2); PHASE_END();

        // PH2: (M1,N1); 8 ds_reads; stage A0(t+2)
        LDA4(1);
        if (tt + 2 < 16) STAGE(0, tt + 2);
        PHASE_TAIL(); MMAQ(4, 2); PHASE_END();

        // PH3: (M1,N0); 0 ds_reads; stage B1(t+2); counted vmcnt
        if (tt + 2 < 16) STAGE(3, tt + 2);
        __builtin_amdgcn_s_barrier();
        __builtin_amdgcn_s_setprio(1);
        MMAQ(4, 0);
        __builtin_amdgcn_s_setprio(0);
        if (tt + 2 < 16)      asm volatile("s_waitcnt vmcnt(4)" ::: "memory");
        else if (tt + 1 < 16) asm volatile("s_waitcnt vmcnt(0)" ::: "memory");
        __builtin_amdgcn_s_barrier();
    }

#undef STAGE
#undef LDA4
#undef LDB2
#undef MMAQ
#undef PHASE_TAIL
#undef PHASE_END

    // epilogue (fragment-local layout logic identical to R7, new geometry)
    const float* bias = (mat == 0) ? b0 : (mat == 1) ? b1 : b2;
    const float scl = (mat == 0) ? 0.125f : 1.0f;
#pragma unroll
    for (int nt = 0; nt < 4; ++nt) {
        int colm = (nb & 3) * 256 + wc * 64 + nt * 16 + l15;  // feature h*64+dh
        float bv = bias[colm];
        int h = colm >> 6, dh = colm & 63;
#pragma unroll
        for (int mt = 0; mt < 8; ++mt) {
            int row0 = mb * 256 + wr * 128 + mt * 16 + quad * 4;
            int b = row0 >> 11, s0 = row0 & 2047;
            int bh = b * 16 + h, g0 = s0 >> 1;                // even
            float v0 = (acc[mt][nt][0] + bv) * scl, v1 = (acc[mt][nt][1] + bv) * scl;
            float v2 = (acc[mt][nt][2] + bv) * scl, v3 = (acc[mt][nt][3] + bv) * scl;
            if (mat == 2) {
                // keys (g0,g0+1): dp=dh from rows r0,r2; dp=dh+64 from r1,r3
                u32 w0 = f2bf1(v0) | (f2bf1(v2) << 16);
                u32 w1 = f2bf1(v1) | (f2bf1(v3) << 16);
                int j6 = g0 & 63;
                int gp = (g0 & ~63) + (j6 & 32) + ((j6 >> 2) & 3) * 8
                       + ((j6 >> 4) & 1) * 4 + (j6 & 3);      // sigma-permuted
                *(u32*)(v_t + ((size_t)(bh * 128 + dh) * 1024 + gp)) = w0;
                *(u32*)(v_t + ((size_t)(bh * 128 + dh + 64) * 1024 + gp)) = w1;
            } else {
                // dp' = 2*dh + (s&1): (r0,r1)->g0, (r2,r3)->g0+1, adjacent u16
                u16* dst = (mat == 0) ? q_att : k_att;
                u32 w0 = f2bf1(v0) | (f2bf1(v1) << 16);
                u32 w1 = f2bf1(v2) | (f2bf1(v3) << 16);
                size_t base = ((size_t)bh * 1024 + g0) * 128 + 2 * dh;
                *(u32*)(dst + base) = w0;
                *(u32*)(dst + base + 128) = w1;
            }
        }
    }
}

// ---------------------------------------------------------------------------
// Kernel 2: flash attention, transposed-S, global_load_lds staging with
// XOR-swizzled LDS. grid (16,64), 256 thr. (unchanged from R7.)
// ---------------------------------------------------------------------------
__global__ __launch_bounds__(256) void attn4(
    const u16* __restrict__ q_att, const u16* __restrict__ k_att,
    const u16* __restrict__ v_t, u16* __restrict__ ctx)
{
    const int bh = blockIdx.y, qb = blockIdx.x;
    const u16* Q = q_att + (size_t)bh * 131072;
    const u16* K = k_att + (size_t)bh * 131072;
    const u16* V = v_t  + (size_t)bh * 131072;     // [d'=128][g-sigma-permuted]

    __shared__ __align__(16) u16 Ks[64 * 128];     // 16KB
    __shared__ __align__(16) u16 Vs[128 * 64];     // 16KB

    const int t = threadIdx.x, wave = t >> 6, lane = t & 63;
    const int l15 = lane & 15, quad = lane >> 4;
    const int q_row = qb * 64 + wave * 16 + l15;

    int offK[4], offV[4];
#pragma unroll
    for (int j = 0; j < 4; ++j) {
        int ck = wave * 4 + j;
        int rowK = ck * 4 + (lane >> 4);                       // 0..63
        offK[j] = rowK * 128 + (((lane & 15) ^ (rowK & 15)) * 8);
        int rowV = ck * 8 + (lane >> 3);                       // d' 0..127
        offV[j] = rowV * 1024 + (((lane & 7) ^ ((lane >> 3) & 7)) * 8);
    }

    short8 bq[4];
#pragma unroll
    for (int kb = 0; kb < 4; ++kb)
        bq[kb] = *(const short8*)(Q + (size_t)q_row * 128 + kb * 32 + quad * 8);

    f32x4 accO[8] = {};
    float m_i = -1e30f, l_i = 0.0f;

    for (int kt = 0; kt < 16; ++kt) {
        const u16* Kt = K + (size_t)kt * 8192;
        const u16* Vt = V + (size_t)kt * 64;
        __syncthreads();                            // prev tile's LDS reads done
#pragma unroll
        for (int j = 0; j < 4; ++j) {
            gld16(Ks + (wave * 4 + j) * 512, Kt + offK[j]);
            gld16(Vs + (wave * 4 + j) * 512, Vt + offV[j]);
        }
        __syncthreads();                            // drains vmcnt incl. lds-DMA

        f32x4 accS[4] = {};
#pragma unroll
        for (int kf = 0; kf < 4; ++kf)
#pragma unroll
            for (int kb = 0; kb < 4; ++kb) {
                short8 ak = *(const short8*)(Ks + (kf * 16 + l15) * 128
                                             + (((kb * 4 + quad) ^ l15) * 8));
                accS[kf] = MFMA16(ak, bq[kb], accS[kf]);
            }

        float mloc = -1e30f;
#pragma unroll
        for (int kf = 0; kf < 4; ++kf)
            mloc = fmaxf(mloc, fmaxf(fmaxf(accS[kf][0], accS[kf][1]),
                                     fmaxf(accS[kf][2], accS[kf][3])));
        mloc = fmaxf(mloc, __shfl_xor(mloc, 16));
        mloc = fmaxf(mloc, __shfl_xor(mloc, 32));
        float mn = fmaxf(m_i, mloc);
        float alpha = __expf(m_i - mn);
        m_i = mn;

        float lsum = 0.0f;
        u32 pb[8];
#pragma unroll
        for (int kf = 0; kf < 4; ++kf) {
            float p0 = __expf(accS[kf][0] - mn);
            float p1 = __expf(accS[kf][1] - mn);
            float p2 = __expf(accS[kf][2] - mn);
            float p3 = __expf(accS[kf][3] - mn);
            lsum += (p0 + p1) + (p2 + p3);
            pb[kf * 2]     = f2bf1(p0) | (f2bf1(p1) << 16);
            pb[kf * 2 + 1] = f2bf1(p2) | (f2bf1(p3) << 16);
        }
        lsum += __shfl_xor(lsum, 16);
        lsum += __shfl_xor(lsum, 32);
        l_i = l_i * alpha + lsum;

#pragma unroll
        for (int f = 0; f < 8; ++f) {
            accO[f][0] *= alpha; accO[f][1] *= alpha;
            accO[f][2] *= alpha; accO[f][3] *= alpha;
        }

        S8 bp0, bp1;
        bp0.u[0] = pb[0]; bp0.u[1] = pb[1]; bp0.u[2] = pb[2]; bp0.u[3] = pb[3];
        bp1.u[0] = pb[4]; bp1.u[1] = pb[5]; bp1.u[2] = pb[6]; bp1.u[3] = pb[7];
        const int l7 = l15 & 7;
#pragma unroll
        for (int df = 0; df < 8; ++df) {
            const u16* vrow = Vs + (df * 16 + l15) * 64;
            short8 av0 = *(const short8*)(vrow + ((quad ^ l7) * 8));
            short8 av1 = *(const short8*)(vrow + (((quad + 4) ^ l7) * 8));
            accO[df] = MFMA16(av0, bp0.s, accO[df]);
            accO[df] = MFMA16(av1, bp1.s, accO[df]);
        }
    }

    const int h = bh & 15, b = bh >> 4;
    float inv = 1.0f / l_i;
    size_t base = ((size_t)(b * 2048 + 2 * q_row + (h >> 3))) * 1024 + (h & 7) * 128;
#pragma unroll
    for (int df = 0; df < 8; ++df) {
        int dp = df * 16 + quad * 4;
        uint2 w;
        w.x = f2bf1(accO[df][0] * inv) | (f2bf1(accO[df][1] * inv) << 16);
        w.y = f2bf1(accO[df][2] * inv) | (f2bf1(accO[df][3] * inv) << 16);
        *(uint2*)(ctx + base + dp) = w;
    }
}

// ---------------------------------------------------------------------------
// Kernel 3: out = ctx(bf16) @ Wob^T + bo -> fp32. 128x128 m97 tile, grid (8,64).
// (256² would drop grid to 128 blocks = half the GPU idle; kept at 128².)
// ---------------------------------------------------------------------------
__global__ __launch_bounds__(256) void out_gemm4(
    const u16* __restrict__ ctx, const u16* __restrict__ Wob,
    const float* __restrict__ bo, float* __restrict__ out)
{
    const int nb = blockIdx.x, mb = blockIdx.y;
    __shared__ __align__(16) u16 As[128 * 32];
    __shared__ __align__(16) u16 Bs[128 * 32];
    const int t = threadIdx.x, wave = t >> 6, lane = t & 63;
    const int l15 = lane & 15, quad = lane >> 4;
    const int wm = (wave >> 1) * 64, wn = (wave & 1) * 64;
    const int lrow = lane >> 2, lcb = (lane & 3) * 8;

    const u16* Ab = ctx + (size_t)(mb * 128) * 1024;
    const u16* Bb = Wob + (size_t)(nb * 128) * 1024;

    f32x4 acc[4][4] = {};

    for (int k0 = 0; k0 < 1024; k0 += 32) {
        __syncthreads();
#pragma unroll
        for (int j = 0; j < 2; ++j) {
            int chunk = wave * 2 + j;
            gld16(As + chunk * 512, Ab + (size_t)(chunk * 16 + lrow) * 1024 + k0 + lcb);
            gld16(Bs + chunk * 512, Bb + (size_t)(chunk * 16 + lrow) * 1024 + k0 + lcb);
        }
        __syncthreads();

        short8 af[4], bf[4];
#pragma unroll
        for (int mt = 0; mt < 4; ++mt)
            af[mt] = *(const short8*)(As + (wm + mt * 16 + l15) * 32 + quad * 8);
#pragma unroll
        for (int nt = 0; nt < 4; ++nt)
            bf[nt] = *(const short8*)(Bs + (wn + nt * 16 + l15) * 32 + quad * 8);
#pragma unroll
        for (int mt = 0; mt < 4; ++mt)
#pragma unroll
            for (int nt = 0; nt < 4; ++nt)
                acc[mt][nt] = MFMA16(af[mt], bf[nt], acc[mt][nt]);
    }

#pragma unroll
    for (int nt = 0; nt < 4; ++nt) {
        int col = nb * 128 + wn + nt * 16 + l15;
        float bv = bo[col];
#pragma unroll
        for (int mt = 0; mt < 4; ++mt)
#pragma unroll
            for (int r = 0; r < 4; ++r) {
                int row = mb * 128 + wm + mt * 16 + quad * 4 + r;
                out[(size_t)row * 1024 + col] = acc[mt][nt][r] + bv;
            }
    }
}

// ---------------------------------------------------------------------------
extern "C" void kernel_launch(void* const* d_in, const int* in_sizes, int n_in,
                              void* d_out, int out_size, void* d_ws, size_t ws_size,
                              hipStream_t stream)
{
    const float* X  = (const float*)d_in[0];
    const float* Wq = (const float*)d_in[1];
    const float* bq = (const float*)d_in[2];
    const float* Wk = (const float*)d_in[3];
    const float* bk = (const float*)d_in[4];
    const float* Wv = (const float*)d_in[5];
    const float* bv = (const float*)d_in[6];
    const float* Wo = (const float*)d_in[7];
    const float* bo = (const float*)d_in[8];

    const size_t M8 = 8388608;
    u16* q_att = (u16*)d_ws;
    u16* k_att = q_att + M8;
    u16* v_t   = k_att + M8;
    u16* Xb    = v_t   + M8;            // Xb dead after qkv -> ctx aliases it
    u16* ctx   = Xb;
    u16* Wcat  = Xb + M8;
    u16* Wob   = Wcat + 3 * 1048576;

    convert<<<dim3(3072), 256, 0, stream>>>(X, Wq, Wk, Wv, Wo, Xb, Wcat, Wob);
    qkv_gemm8<<<dim3(12, 32), 512, 0, stream>>>(Xb, Wcat, bq, bk, bv,
                                                q_att, k_att, v_t);
    attn4<<<dim3(16, 64), 256, 0, stream>>>(q_att, k_att, v_t, ctx);
    out_gemm4<<<dim3(8, 64), 256, 0, stream>>>(ctx, Wob, bo, (float*)d_out);
}

// Round 2
// 263.697 us; speedup vs baseline: 1.0183x; 1.0168x over previous
//
#include <hip/hip_runtime.h>

// GPT2 grouped-query attention, bf16 MFMA pipeline, round 9.
// R9: back to the proven m97 regime (128^2 tile, 2-phase, multi-block/CU
// implicit overlap) but with BK=64 (half the barriers, 32 MFMA/step) and
// R8's proven XOR-swizzle (pre-swizzled global_load_lds source + swizzled
// ds_read) -> zero bank conflicts at the 128B row stride.
// __launch_bounds__(256,3): cap VGPR ~170 -> 12 waves/CU = 3 blocks/CU.
// ws (u16 elems): q_att[8M] | k_att[8M] | v_t[8M] | Xb/ctx[8M] | Wcat[3M] | Wob[1M]

typedef __attribute__((ext_vector_type(8))) short short8;
typedef __attribute__((ext_vector_type(4))) float f32x4;
typedef unsigned int u32;
typedef unsigned short u16;

#define MFMA16(a, b, c) __builtin_amdgcn_mfma_f32_16x16x32_bf16((a), (b), (c), 0, 0, 0)

union S8 { short8 s; uint2 v[2]; u32 u[4]; };

__device__ __forceinline__ u32 f2bf1(float x) {
    union { float f; u32 u; } v; v.f = x;
    return (v.u + 0x7fffu + ((v.u >> 16) & 1u)) >> 16;   // RNE
}

__device__ __forceinline__ void gld16(u16* lds, const u16* g) {
    __builtin_amdgcn_global_load_lds(
        (const __attribute__((address_space(1))) unsigned int*)(g),
        (__attribute__((address_space(3))) unsigned int*)(lds),
        16, 0, 0);
}

// ---------------------------------------------------------------------------
// Kernel 0: fp32 -> bf16 convert.
// ---------------------------------------------------------------------------
__global__ __launch_bounds__(256) void convert(
    const float* __restrict__ X, const float* __restrict__ Wq,
    const float* __restrict__ Wk, const float* __restrict__ Wv,
    const float* __restrict__ Wo,
    u16* __restrict__ Xb, u16* __restrict__ Wcat, u16* __restrict__ Wob)
{
    const size_t M8 = 8388608, M1 = 1048576;
    size_t i = ((size_t)blockIdx.x * 256 + threadIdx.x) * 16;
    const float* src; u16* dst;
    if (i < M8)              { src = X  + i;                dst = Xb   + i; }
    else if (i < M8 + M1)    { src = Wq + (i - M8);         dst = Wcat + (i - M8); }
    else if (i < M8 + 2*M1)  { src = Wk + (i - M8 - M1);    dst = Wcat + (i - M8); }
    else if (i < M8 + 3*M1)  { src = Wv + (i - M8 - 2*M1);  dst = Wcat + (i - M8); }
    else                     { src = Wo + (i - M8 - 3*M1);  dst = Wob  + (i - M8 - 3*M1); }
#pragma unroll
    for (int j = 0; j < 2; ++j) {
        float4 a = ((const float4*)src)[2 * j];
        float4 b = ((const float4*)src)[2 * j + 1];
        uint4 o;
        o.x = f2bf1(a.x) | (f2bf1(a.y) << 16);
        o.y = f2bf1(a.z) | (f2bf1(a.w) << 16);
        o.z = f2bf1(b.x) | (f2bf1(b.y) << 16);
        o.w = f2bf1(b.z) | (f2bf1(b.w) << 16);
        ((uint4*)dst)[j] = o;
    }
}

// ---------------------------------------------------------------------------
// Kernel 1: fused QKV GEMM. C[8192][3072] = Xb @ Wcat^T. 128x128 tile, BK=64,
// swizzled LDS (chunk ^= row&7), 16 K-steps (half of R7's 32 barriers).
// q/k layout: [bh][g][dp'] with dp' = 2*dh + (s&1); v_t: [bh][dp][g-sigma].
// ---------------------------------------------------------------------------
__global__ __launch_bounds__(256, 3) void qkv_gemm9(
    const u16* __restrict__ Xb, const u16* __restrict__ Wcat,
    const float* __restrict__ b0, const float* __restrict__ b1,
    const float* __restrict__ b2,
    u16* __restrict__ q_att, u16* __restrict__ k_att, u16* __restrict__ v_t)
{
    const int nb = blockIdx.x, mb = blockIdx.y;
    const int mat = nb >> 3;

    __shared__ __align__(16) u16 As[128 * 64];   // 16 KB
    __shared__ __align__(16) u16 Bs[128 * 64];   // 16 KB

    const int t = threadIdx.x, wave = t >> 6, lane = t & 63;
    const int l15 = lane & 15, quad = lane >> 4;
    const int wm = (wave >> 1) * 64, wn = (wave & 1) * 64;

    // staging: thread t covers row (c*32 + t>>3), 16B chunk (t&7), with
    // source chunk pre-swizzled by row&7 so LDS holds [row][chunk ^ (row&7)].
    const int srow = t >> 3;                               // 0..31
    const int scol = ((t & 7) ^ (srow & 7)) * 8;           // swizzled src chunk
    u16* ldsA = As + wave * 512;                           // + lane*8 by DMA
    u16* ldsB = Bs + wave * 512;

    const u16* Ab = Xb   + (size_t)(mb * 128) * 1024;
    const u16* Bb = Wcat + (size_t)(nb * 128) * 1024;

    // frag-read swizzle: logical chunk (ks*4+quad) ^ (row&7); row&7 == l15&7
    const int swz = l15 & 7;

    f32x4 acc[4][4] = {};

    for (int k0 = 0; k0 < 1024; k0 += 64) {
        __syncthreads();
#pragma unroll
        for (int c = 0; c < 4; ++c) {
            size_t so = (size_t)(c * 32 + srow) * 1024 + k0 + scol;
            gld16(ldsA + c * 2048, Ab + so);
            gld16(ldsB + c * 2048, Bb + so);
        }
        __syncthreads();

#pragma unroll
        for (int ks = 0; ks < 2; ++ks) {
            short8 af[4], bf[4];
            const int ck = ((ks * 4 + quad) ^ swz) * 8;
#pragma unroll
            for (int mt = 0; mt < 4; ++mt)
                af[mt] = *(const short8*)(As + (wm + mt * 16 + l15) * 64 + ck);
#pragma unroll
            for (int nt = 0; nt < 4; ++nt)
                bf[nt] = *(const short8*)(Bs + (wn + nt * 16 + l15) * 64 + ck);
#pragma unroll
            for (int mt = 0; mt < 4; ++mt)
#pragma unroll
                for (int nt = 0; nt < 4; ++nt)
                    acc[mt][nt] = MFMA16(af[mt], bf[nt], acc[mt][nt]);
        }
    }

    const float* bias = (mat == 0) ? b0 : (mat == 1) ? b1 : b2;
    const float scl = (mat == 0) ? 0.125f : 1.0f;
#pragma unroll
    for (int nt = 0; nt < 4; ++nt) {
        int colm = (nb & 7) * 128 + wn + nt * 16 + l15;   // feature = h*64+dh
        float bv = bias[colm];
        int h = colm >> 6, dh = colm & 63;
#pragma unroll
        for (int mt = 0; mt < 4; ++mt) {
            int row0 = mb * 128 + wm + mt * 16 + quad * 4;
            int b = row0 >> 11, s0 = row0 & 2047;
            int bh = b * 16 + h, g0 = s0 >> 1;                // even
            float v0 = (acc[mt][nt][0] + bv) * scl, v1 = (acc[mt][nt][1] + bv) * scl;
            float v2 = (acc[mt][nt][2] + bv) * scl, v3 = (acc[mt][nt][3] + bv) * scl;
            if (mat == 2) {
                // keys (g0,g0+1): dp=dh from rows r0,r2; dp=dh+64 from r1,r3
                u32 w0 = f2bf1(v0) | (f2bf1(v2) << 16);
                u32 w1 = f2bf1(v1) | (f2bf1(v3) << 16);
                int j6 = g0 & 63;
                int gp = (g0 & ~63) + (j6 & 32) + ((j6 >> 2) & 3) * 8
                       + ((j6 >> 4) & 1) * 4 + (j6 & 3);      // sigma-permuted
                *(u32*)(v_t + ((size_t)(bh * 128 + dh) * 1024 + gp)) = w0;
                *(u32*)(v_t + ((size_t)(bh * 128 + dh + 64) * 1024 + gp)) = w1;
            } else {
                // dp' = 2*dh + (s&1): (r0,r1)->g0, (r2,r3)->g0+1, adjacent u16
                u16* dst = (mat == 0) ? q_att : k_att;
                u32 w0 = f2bf1(v0) | (f2bf1(v1) << 16);
                u32 w1 = f2bf1(v2) | (f2bf1(v3) << 16);
                size_t base = ((size_t)bh * 1024 + g0) * 128 + 2 * dh;
                *(u32*)(dst + base) = w0;
                *(u32*)(dst + base + 128) = w1;
            }
        }
    }
}

// ---------------------------------------------------------------------------
// Kernel 2: flash attention, transposed-S, global_load_lds staging with
// XOR-swizzled LDS. grid (16,64), 256 thr. (unchanged from R7.)
// ---------------------------------------------------------------------------
__global__ __launch_bounds__(256) void attn4(
    const u16* __restrict__ q_att, const u16* __restrict__ k_att,
    const u16* __restrict__ v_t, u16* __restrict__ ctx)
{
    const int bh = blockIdx.y, qb = blockIdx.x;
    const u16* Q = q_att + (size_t)bh * 131072;
    const u16* K = k_att + (size_t)bh * 131072;
    const u16* V = v_t  + (size_t)bh * 131072;     // [d'=128][g-sigma-permuted]

    __shared__ __align__(16) u16 Ks[64 * 128];     // 16KB
    __shared__ __align__(16) u16 Vs[128 * 64];     // 16KB

    const int t = threadIdx.x, wave = t >> 6, lane = t & 63;
    const int l15 = lane & 15, quad = lane >> 4;
    const int q_row = qb * 64 + wave * 16 + l15;

    int offK[4], offV[4];
#pragma unroll
    for (int j = 0; j < 4; ++j) {
        int ck = wave * 4 + j;
        int rowK = ck * 4 + (lane >> 4);                       // 0..63
        offK[j] = rowK * 128 + (((lane & 15) ^ (rowK & 15)) * 8);
        int rowV = ck * 8 + (lane >> 3);                       // d' 0..127
        offV[j] = rowV * 1024 + (((lane & 7) ^ ((lane >> 3) & 7)) * 8);
    }

    short8 bq[4];
#pragma unroll
    for (int kb = 0; kb < 4; ++kb)
        bq[kb] = *(const short8*)(Q + (size_t)q_row * 128 + kb * 32 + quad * 8);

    f32x4 accO[8] = {};
    float m_i = -1e30f, l_i = 0.0f;

    for (int kt = 0; kt < 16; ++kt) {
        const u16* Kt = K + (size_t)kt * 8192;
        const u16* Vt = V + (size_t)kt * 64;
        __syncthreads();                            // prev tile's LDS reads done
#pragma unroll
        for (int j = 0; j < 4; ++j) {
            gld16(Ks + (wave * 4 + j) * 512, Kt + offK[j]);
            gld16(Vs + (wave * 4 + j) * 512, Vt + offV[j]);
        }
        __syncthreads();                            // drains vmcnt incl. lds-DMA

        f32x4 accS[4] = {};
#pragma unroll
        for (int kf = 0; kf < 4; ++kf)
#pragma unroll
            for (int kb = 0; kb < 4; ++kb) {
                short8 ak = *(const short8*)(Ks + (kf * 16 + l15) * 128
                                             + (((kb * 4 + quad) ^ l15) * 8));
                accS[kf] = MFMA16(ak, bq[kb], accS[kf]);
            }

        float mloc = -1e30f;
#pragma unroll
        for (int kf = 0; kf < 4; ++kf)
            mloc = fmaxf(mloc, fmaxf(fmaxf(accS[kf][0], accS[kf][1]),
                                     fmaxf(accS[kf][2], accS[kf][3])));
        mloc = fmaxf(mloc, __shfl_xor(mloc, 16));
        mloc = fmaxf(mloc, __shfl_xor(mloc, 32));
        float mn = fmaxf(m_i, mloc);
        float alpha = __expf(m_i - mn);
        m_i = mn;

        float lsum = 0.0f;
        u32 pb[8];
#pragma unroll
        for (int kf = 0; kf < 4; ++kf) {
            float p0 = __expf(accS[kf][0] - mn);
            float p1 = __expf(accS[kf][1] - mn);
            float p2 = __expf(accS[kf][2] - mn);
            float p3 = __expf(accS[kf][3] - mn);
            lsum += (p0 + p1) + (p2 + p3);
            pb[kf * 2]     = f2bf1(p0) | (f2bf1(p1) << 16);
            pb[kf * 2 + 1] = f2bf1(p2) | (f2bf1(p3) << 16);
        }
        lsum += __shfl_xor(lsum, 16);
        lsum += __shfl_xor(lsum, 32);
        l_i = l_i * alpha + lsum;

#pragma unroll
        for (int f = 0; f < 8; ++f) {
            accO[f][0] *= alpha; accO[f][1] *= alpha;
            accO[f][2] *= alpha; accO[f][3] *= alpha;
        }

        S8 bp0, bp1;
        bp0.u[0] = pb[0]; bp0.u[1] = pb[1]; bp0.u[2] = pb[2]; bp0.u[3] = pb[3];
        bp1.u[0] = pb[4]; bp1.u[1] = pb[5]; bp1.u[2] = pb[6]; bp1.u[3] = pb[7];
        const int l7 = l15 & 7;
#pragma unroll
        for (int df = 0; df < 8; ++df) {
            const u16* vrow = Vs + (df * 16 + l15) * 64;
            short8 av0 = *(const short8*)(vrow + ((quad ^ l7) * 8));
            short8 av1 = *(const short8*)(vrow + (((quad + 4) ^ l7) * 8));
            accO[df] = MFMA16(av0, bp0.s, accO[df]);
            accO[df] = MFMA16(av1, bp1.s, accO[df]);
        }
    }

    const int h = bh & 15, b = bh >> 4;
    float inv = 1.0f / l_i;
    size_t base = ((size_t)(b * 2048 + 2 * q_row + (h >> 3))) * 1024 + (h & 7) * 128;
#pragma unroll
    for (int df = 0; df < 8; ++df) {
        int dp = df * 16 + quad * 4;
        uint2 w;
        w.x = f2bf1(accO[df][0] * inv) | (f2bf1(accO[df][1] * inv) << 16);
        w.y = f2bf1(accO[df][2] * inv) | (f2bf1(accO[df][3] * inv) << 16);
        *(uint2*)(ctx + base + dp) = w;
    }
}

// ---------------------------------------------------------------------------
// Kernel 3: out = ctx(bf16) @ Wob^T + bo -> fp32. Same BK=64+swizzle
// treatment as qkv_gemm9. grid (8,64).
// ---------------------------------------------------------------------------
__global__ __launch_bounds__(256, 3) void out_gemm9(
    const u16* __restrict__ ctx, const u16* __restrict__ Wob,
    const float* __restrict__ bo, float* __restrict__ out)
{
    const int nb = blockIdx.x, mb = blockIdx.y;
    __shared__ __align__(16) u16 As[128 * 64];
    __shared__ __align__(16) u16 Bs[128 * 64];
    const int t = threadIdx.x, wave = t >> 6, lane = t & 63;
    const int l15 = lane & 15, quad = lane >> 4;
    const int wm = (wave >> 1) * 64, wn = (wave & 1) * 64;

    const int srow = t >> 3;
    const int scol = ((t & 7) ^ (srow & 7)) * 8;
    u16* ldsA = As + wave * 512;
    u16* ldsB = Bs + wave * 512;

    const u16* Ab = ctx + (size_t)(mb * 128) * 1024;
    const u16* Bb = Wob + (size_t)(nb * 128) * 1024;

    const int swz = l15 & 7;

    f32x4 acc[4][4] = {};

    for (int k0 = 0; k0 < 1024; k0 += 64) {
        __syncthreads();
#pragma unroll
        for (int c = 0; c < 4; ++c) {
            size_t so = (size_t)(c * 32 + srow) * 1024 + k0 + scol;
            gld16(ldsA + c * 2048, Ab + so);
            gld16(ldsB + c * 2048, Bb + so);
        }
        __syncthreads();

#pragma unroll
        for (int ks = 0; ks < 2; ++ks) {
            short8 af[4], bf[4];
            const int ck = ((ks * 4 + quad) ^ swz) * 8;
#pragma unroll
            for (int mt = 0; mt < 4; ++mt)
                af[mt] = *(const short8*)(As + (wm + mt * 16 + l15) * 64 + ck);
#pragma unroll
            for (int nt = 0; nt < 4; ++nt)
                bf[nt] = *(const short8*)(Bs + (wn + nt * 16 + l15) * 64 + ck);
#pragma unroll
            for (int mt = 0; mt < 4; ++mt)
#pragma unroll
                for (int nt = 0; nt < 4; ++nt)
                    acc[mt][nt] = MFMA16(af[mt], bf[nt], acc[mt][nt]);
        }
    }

#pragma unroll
    for (int nt = 0; nt < 4; ++nt) {
        int col = nb * 128 + wn + nt * 16 + l15;
        float bv = bo[col];
#pragma unroll
        for (int mt = 0; mt < 4; ++mt)
#pragma unroll
            for (int r = 0; r < 4; ++r) {
                int row = mb * 128 + wm + mt * 16 + quad * 4 + r;
                out[(size_t)row * 1024 + col] = acc[mt][nt][r] + bv;
            }
    }
}

// ---------------------------------------------------------------------------
extern "C" void kernel_launch(void* const* d_in, const int* in_sizes, int n_in,
                              void* d_out, int out_size, void* d_ws, size_t ws_size,
                              hipStream_t stream)
{
    const float* X  = (const float*)d_in[0];
    const float* Wq = (const float*)d_in[1];
    const float* bq = (const float*)d_in[2];
    const float* Wk = (const float*)d_in[3];
    const float* bk = (const float*)d_in[4];
    const float* Wv = (const float*)d_in[5];
    const float* bv = (const float*)d_in[6];
    const float* Wo = (const float*)d_in[7];
    const float* bo = (const float*)d_in[8];

    const size_t M8 = 8388608;
    u16* q_att = (u16*)d_ws;
    u16* k_att = q_att + M8;
    u16* v_t   = k_att + M8;
    u16* Xb    = v_t   + M8;            // Xb dead after qkv -> ctx aliases it
    u16* ctx   = Xb;
    u16* Wcat  = Xb + M8;
    u16* Wob   = Wcat + 3 * 1048576;

    convert<<<dim3(3072), 256, 0, stream>>>(X, Wq, Wk, Wv, Wo, Xb, Wcat, Wob);
    qkv_gemm9<<<dim3(24, 64), 256, 0, stream>>>(Xb, Wcat, bq, bk, bv,
                                                q_att, k_att, v_t);
    attn4<<<dim3(16, 64), 256, 0, stream>>>(q_att, k_att, v_t, ctx);
    out_gemm9<<<dim3(8, 64), 256, 0, stream>>>(ctx, Wob, bo, (float*)d_out);
}

// Round 3
// 238.130 us; speedup vs baseline: 1.1277x; 1.1074x over previous
//
#include <hip/hip_runtime.h>

// GPT2 grouped-query attention, bf16 MFMA pipeline, round 10.
// R10: attn rewritten: QBLK=128/block (grid 8 qb x 64 bh, transposed so one
// bh's blocks share an XCD), K/V LDS double-buffered (stage t+1 before
// compute t -> drain is free), shared ds_reads across 2 q-groups,
// v_cvt_pk_bf16_f32 P-packing, defer-max rescale (THR=8), setprio on MFMA.
// qkv/out GEMMs unchanged from R9 (BK=64 + swizzle, below attn now).
// ws (u16 elems): q_att[8M] | k_att[8M] | v_t[8M] | Xb/ctx[8M] | Wcat[3M] | Wob[1M]

typedef __attribute__((ext_vector_type(8))) short short8;
typedef __attribute__((ext_vector_type(4))) float f32x4;
typedef unsigned int u32;
typedef unsigned short u16;

#define MFMA16(a, b, c) __builtin_amdgcn_mfma_f32_16x16x32_bf16((a), (b), (c), 0, 0, 0)

union S8 { short8 s; uint2 v[2]; u32 u[4]; };

__device__ __forceinline__ u32 f2bf1(float x) {
    union { float f; u32 u; } v; v.f = x;
    return (v.u + 0x7fffu + ((v.u >> 16) & 1u)) >> 16;   // RNE
}

__device__ __forceinline__ u32 cvtpk(float lo, float hi) {
    u32 r;
    asm("v_cvt_pk_bf16_f32 %0, %1, %2" : "=v"(r) : "v"(lo), "v"(hi));
    return r;
}

__device__ __forceinline__ void gld16(u16* lds, const u16* g) {
    __builtin_amdgcn_global_load_lds(
        (const __attribute__((address_space(1))) unsigned int*)(g),
        (__attribute__((address_space(3))) unsigned int*)(lds),
        16, 0, 0);
}

// ---------------------------------------------------------------------------
// Kernel 0: fp32 -> bf16 convert.
// ---------------------------------------------------------------------------
__global__ __launch_bounds__(256) void convert(
    const float* __restrict__ X, const float* __restrict__ Wq,
    const float* __restrict__ Wk, const float* __restrict__ Wv,
    const float* __restrict__ Wo,
    u16* __restrict__ Xb, u16* __restrict__ Wcat, u16* __restrict__ Wob)
{
    const size_t M8 = 8388608, M1 = 1048576;
    size_t i = ((size_t)blockIdx.x * 256 + threadIdx.x) * 16;
    const float* src; u16* dst;
    if (i < M8)              { src = X  + i;                dst = Xb   + i; }
    else if (i < M8 + M1)    { src = Wq + (i - M8);         dst = Wcat + (i - M8); }
    else if (i < M8 + 2*M1)  { src = Wk + (i - M8 - M1);    dst = Wcat + (i - M8); }
    else if (i < M8 + 3*M1)  { src = Wv + (i - M8 - 2*M1);  dst = Wcat + (i - M8); }
    else                     { src = Wo + (i - M8 - 3*M1);  dst = Wob  + (i - M8 - 3*M1); }
#pragma unroll
    for (int j = 0; j < 2; ++j) {
        float4 a = ((const float4*)src)[2 * j];
        float4 b = ((const float4*)src)[2 * j + 1];
        uint4 o;
        o.x = f2bf1(a.x) | (f2bf1(a.y) << 16);
        o.y = f2bf1(a.z) | (f2bf1(a.w) << 16);
        o.z = f2bf1(b.x) | (f2bf1(b.y) << 16);
        o.w = f2bf1(b.z) | (f2bf1(b.w) << 16);
        ((uint4*)dst)[j] = o;
    }
}

// ---------------------------------------------------------------------------
// Kernel 1: fused QKV GEMM. C[8192][3072] = Xb @ Wcat^T. 128x128 tile, BK=64,
// swizzled LDS (chunk ^= row&7). Unchanged from R9.
// ---------------------------------------------------------------------------
__global__ __launch_bounds__(256, 3) void qkv_gemm9(
    const u16* __restrict__ Xb, const u16* __restrict__ Wcat,
    const float* __restrict__ b0, const float* __restrict__ b1,
    const float* __restrict__ b2,
    u16* __restrict__ q_att, u16* __restrict__ k_att, u16* __restrict__ v_t)
{
    const int nb = blockIdx.x, mb = blockIdx.y;
    const int mat = nb >> 3;

    __shared__ __align__(16) u16 As[128 * 64];   // 16 KB
    __shared__ __align__(16) u16 Bs[128 * 64];   // 16 KB

    const int t = threadIdx.x, wave = t >> 6, lane = t & 63;
    const int l15 = lane & 15, quad = lane >> 4;
    const int wm = (wave >> 1) * 64, wn = (wave & 1) * 64;

    const int srow = t >> 3;                               // 0..31
    const int scol = ((t & 7) ^ (srow & 7)) * 8;           // swizzled src chunk
    u16* ldsA = As + wave * 512;
    u16* ldsB = Bs + wave * 512;

    const u16* Ab = Xb   + (size_t)(mb * 128) * 1024;
    const u16* Bb = Wcat + (size_t)(nb * 128) * 1024;

    const int swz = l15 & 7;

    f32x4 acc[4][4] = {};

    for (int k0 = 0; k0 < 1024; k0 += 64) {
        __syncthreads();
#pragma unroll
        for (int c = 0; c < 4; ++c) {
            size_t so = (size_t)(c * 32 + srow) * 1024 + k0 + scol;
            gld16(ldsA + c * 2048, Ab + so);
            gld16(ldsB + c * 2048, Bb + so);
        }
        __syncthreads();

#pragma unroll
        for (int ks = 0; ks < 2; ++ks) {
            short8 af[4], bf[4];
            const int ck = ((ks * 4 + quad) ^ swz) * 8;
#pragma unroll
            for (int mt = 0; mt < 4; ++mt)
                af[mt] = *(const short8*)(As + (wm + mt * 16 + l15) * 64 + ck);
#pragma unroll
            for (int nt = 0; nt < 4; ++nt)
                bf[nt] = *(const short8*)(Bs + (wn + nt * 16 + l15) * 64 + ck);
#pragma unroll
            for (int mt = 0; mt < 4; ++mt)
#pragma unroll
                for (int nt = 0; nt < 4; ++nt)
                    acc[mt][nt] = MFMA16(af[mt], bf[nt], acc[mt][nt]);
        }
    }

    const float* bias = (mat == 0) ? b0 : (mat == 1) ? b1 : b2;
    const float scl = (mat == 0) ? 0.125f : 1.0f;
#pragma unroll
    for (int nt = 0; nt < 4; ++nt) {
        int colm = (nb & 7) * 128 + wn + nt * 16 + l15;   // feature = h*64+dh
        float bv = bias[colm];
        int h = colm >> 6, dh = colm & 63;
#pragma unroll
        for (int mt = 0; mt < 4; ++mt) {
            int row0 = mb * 128 + wm + mt * 16 + quad * 4;
            int b = row0 >> 11, s0 = row0 & 2047;
            int bh = b * 16 + h, g0 = s0 >> 1;                // even
            float v0 = (acc[mt][nt][0] + bv) * scl, v1 = (acc[mt][nt][1] + bv) * scl;
            float v2 = (acc[mt][nt][2] + bv) * scl, v3 = (acc[mt][nt][3] + bv) * scl;
            if (mat == 2) {
                u32 w0 = f2bf1(v0) | (f2bf1(v2) << 16);
                u32 w1 = f2bf1(v1) | (f2bf1(v3) << 16);
                int j6 = g0 & 63;
                int gp = (g0 & ~63) + (j6 & 32) + ((j6 >> 2) & 3) * 8
                       + ((j6 >> 4) & 1) * 4 + (j6 & 3);      // sigma-permuted
                *(u32*)(v_t + ((size_t)(bh * 128 + dh) * 1024 + gp)) = w0;
                *(u32*)(v_t + ((size_t)(bh * 128 + dh + 64) * 1024 + gp)) = w1;
            } else {
                u16* dst = (mat == 0) ? q_att : k_att;
                u32 w0 = f2bf1(v0) | (f2bf1(v1) << 16);
                u32 w1 = f2bf1(v2) | (f2bf1(v3) << 16);
                size_t base = ((size_t)bh * 1024 + g0) * 128 + 2 * dh;
                *(u32*)(dst + base) = w0;
                *(u32*)(dst + base + 128) = w1;
            }
        }
    }
}

// ---------------------------------------------------------------------------
// Kernel 2: flash attention, R10. QBLK=128 per block (2 q-groups/wave),
// double-buffered K/V LDS (stage t+1 during compute t), shared K/V ds_reads
// across q-groups, cvt_pk P-packing, defer-max (THR=8), setprio on MFMA.
// grid (64 bh, 8 qb) so one bh's 8 blocks share an XCD (K/V L2-resident).
// ---------------------------------------------------------------------------
__global__ __launch_bounds__(256, 2) void attn5(
    const u16* __restrict__ q_att, const u16* __restrict__ k_att,
    const u16* __restrict__ v_t, u16* __restrict__ ctx)
{
    const int bh = blockIdx.x, qb = blockIdx.y;
    const u16* Q = q_att + (size_t)bh * 131072;
    const u16* K = k_att + (size_t)bh * 131072;
    const u16* V = v_t  + (size_t)bh * 131072;     // [d'=128][g-sigma-permuted]

    __shared__ __align__(16) u16 Ks[2][64 * 128];  // 32 KB
    __shared__ __align__(16) u16 Vs[2][128 * 64];  // 32 KB

    const int t = threadIdx.x, wave = t >> 6, lane = t & 63;
    const int l15 = lane & 15, quad = lane >> 4;

    // staging source offsets (u16 units), pre-swizzled
    int offK[4], offV[4];
#pragma unroll
    for (int j = 0; j < 4; ++j) {
        int ck = wave * 4 + j;
        int rowK = ck * 4 + (lane >> 4);                       // 0..63
        offK[j] = rowK * 128 + (((lane & 15) ^ (rowK & 15)) * 8);
        int rowV = ck * 8 + (lane >> 3);                       // d' 0..127
        offV[j] = rowV * 1024 + (((lane & 7) ^ ((lane >> 3) & 7)) * 8);
    }

#define ASTAGE(pp, kt) do {                                                   \
        const u16* Kt_ = K + (size_t)(kt) * 8192;                             \
        const u16* Vt_ = V + (size_t)(kt) * 64;                               \
        _Pragma("unroll")                                                     \
        for (int j_ = 0; j_ < 4; ++j_) {                                      \
            gld16(&Ks[(pp)][(wave * 4 + j_) * 512], Kt_ + offK[j_]);          \
            gld16(&Vs[(pp)][(wave * 4 + j_) * 512], Vt_ + offV[j_]);          \
        }                                                                     \
    } while (0)

    // Q^T B-frags for both q-groups: q_row = qb*128 + wave*32 + qg*16 + l15
    short8 bq[2][4];
#pragma unroll
    for (int qg = 0; qg < 2; ++qg) {
        const int qr = qb * 128 + wave * 32 + qg * 16 + l15;
#pragma unroll
        for (int kb = 0; kb < 4; ++kb)
            bq[qg][kb] = *(const short8*)(Q + (size_t)qr * 128 + kb * 32 + quad * 8);
    }

    f32x4 accO[2][8] = {};
    float m_i[2] = {-1e30f, -1e30f}, l_i[2] = {0.0f, 0.0f};

    ASTAGE(0, 0);
    __syncthreads();                               // buf0 staged & visible

    for (int kt = 0; kt < 16; ++kt) {
        const int p = kt & 1;
        if (kt + 1 < 16) ASTAGE(p ^ 1, kt + 1);    // overlap with compute below
        const u16* Ksp = &Ks[p][0];
        const u16* Vsp = &Vs[p][0];

        // S^T = K x Q^T, shared K-frag across both q-groups
        f32x4 accS[2][4] = {};
        __builtin_amdgcn_s_setprio(1);
#pragma unroll
        for (int kf = 0; kf < 4; ++kf)
#pragma unroll
            for (int kb = 0; kb < 4; ++kb) {
                short8 ak = *(const short8*)(Ksp + (kf * 16 + l15) * 128
                                             + (((kb * 4 + quad) ^ l15) * 8));
                accS[0][kf] = MFMA16(ak, bq[0][kb], accS[0][kf]);
                accS[1][kf] = MFMA16(ak, bq[1][kb], accS[1][kf]);
            }
        __builtin_amdgcn_s_setprio(0);

        // softmax per q-group: defer-max + cvt_pk packing
        u32 pb[2][8];
#pragma unroll
        for (int qg = 0; qg < 2; ++qg) {
            float mloc = -1e30f;
#pragma unroll
            for (int kf = 0; kf < 4; ++kf)
                mloc = fmaxf(mloc, fmaxf(fmaxf(accS[qg][kf][0], accS[qg][kf][1]),
                                         fmaxf(accS[qg][kf][2], accS[qg][kf][3])));
            mloc = fmaxf(mloc, __shfl_xor(mloc, 16));
            mloc = fmaxf(mloc, __shfl_xor(mloc, 32));

            if (!__all(mloc - m_i[qg] <= 8.0f)) {   // rescale only on max growth
                float mn = fmaxf(m_i[qg], mloc);
                float alpha = __expf(m_i[qg] - mn);
#pragma unroll
                for (int f = 0; f < 8; ++f) {
                    accO[qg][f][0] *= alpha; accO[qg][f][1] *= alpha;
                    accO[qg][f][2] *= alpha; accO[qg][f][3] *= alpha;
                }
                l_i[qg] *= alpha;
                m_i[qg] = mn;
            }

            float lsum = 0.0f;
            const float mi = m_i[qg];
#pragma unroll
            for (int kf = 0; kf < 4; ++kf) {
                float p0 = __expf(accS[qg][kf][0] - mi);
                float p1 = __expf(accS[qg][kf][1] - mi);
                float p2 = __expf(accS[qg][kf][2] - mi);
                float p3 = __expf(accS[qg][kf][3] - mi);
                lsum += (p0 + p1) + (p2 + p3);
                pb[qg][kf * 2]     = cvtpk(p0, p1);
                pb[qg][kf * 2 + 1] = cvtpk(p2, p3);
            }
            lsum += __shfl_xor(lsum, 16);
            lsum += __shfl_xor(lsum, 32);
            l_i[qg] += lsum;
        }

        // PV: O^T += V^T @ P^T, shared V-frags across both q-groups
        S8 bp00, bp01, bp10, bp11;
        bp00.u[0] = pb[0][0]; bp00.u[1] = pb[0][1]; bp00.u[2] = pb[0][2]; bp00.u[3] = pb[0][3];
        bp01.u[0] = pb[0][4]; bp01.u[1] = pb[0][5]; bp01.u[2] = pb[0][6]; bp01.u[3] = pb[0][7];
        bp10.u[0] = pb[1][0]; bp10.u[1] = pb[1][1]; bp10.u[2] = pb[1][2]; bp10.u[3] = pb[1][3];
        bp11.u[0] = pb[1][4]; bp11.u[1] = pb[1][5]; bp11.u[2] = pb[1][6]; bp11.u[3] = pb[1][7];
        const int l7 = l15 & 7;
        __builtin_amdgcn_s_setprio(1);
#pragma unroll
        for (int df = 0; df < 8; ++df) {
            const u16* vrow = Vsp + (df * 16 + l15) * 64;
            short8 av0 = *(const short8*)(vrow + ((quad ^ l7) * 8));
            short8 av1 = *(const short8*)(vrow + (((quad + 4) ^ l7) * 8));
            accO[0][df] = MFMA16(av0, bp00.s, accO[0][df]);
            accO[0][df] = MFMA16(av1, bp01.s, accO[0][df]);
            accO[1][df] = MFMA16(av0, bp10.s, accO[1][df]);
            accO[1][df] = MFMA16(av1, bp11.s, accO[1][df]);
        }
        __builtin_amdgcn_s_setprio(0);

        if (kt + 1 < 16) __syncthreads();          // drains t+1 stage; all reads of p done
    }
#undef ASTAGE

    // epilogue: O^T/l -> ctx[b][sp=2q+(h>>3)][(h&7)*128 + d'], 8B stores
    const int h = bh & 15, b = bh >> 4;
#pragma unroll
    for (int qg = 0; qg < 2; ++qg) {
        const int qr = qb * 128 + wave * 32 + qg * 16 + l15;
        float inv = 1.0f / l_i[qg];
        size_t base = ((size_t)(b * 2048 + 2 * qr + (h >> 3))) * 1024 + (h & 7) * 128;
#pragma unroll
        for (int df = 0; df < 8; ++df) {
            int dp = df * 16 + quad * 4;
            uint2 w;
            w.x = f2bf1(accO[qg][df][0] * inv) | (f2bf1(accO[qg][df][1] * inv) << 16);
            w.y = f2bf1(accO[qg][df][2] * inv) | (f2bf1(accO[qg][df][3] * inv) << 16);
            *(uint2*)(ctx + base + dp) = w;
        }
    }
}

// ---------------------------------------------------------------------------
// Kernel 3: out = ctx(bf16) @ Wob^T + bo -> fp32. BK=64 + swizzle (R9).
// ---------------------------------------------------------------------------
__global__ __launch_bounds__(256, 3) void out_gemm9(
    const u16* __restrict__ ctx, const u16* __restrict__ Wob,
    const float* __restrict__ bo, float* __restrict__ out)
{
    const int nb = blockIdx.x, mb = blockIdx.y;
    __shared__ __align__(16) u16 As[128 * 64];
    __shared__ __align__(16) u16 Bs[128 * 64];
    const int t = threadIdx.x, wave = t >> 6, lane = t & 63;
    const int l15 = lane & 15, quad = lane >> 4;
    const int wm = (wave >> 1) * 64, wn = (wave & 1) * 64;

    const int srow = t >> 3;
    const int scol = ((t & 7) ^ (srow & 7)) * 8;
    u16* ldsA = As + wave * 512;
    u16* ldsB = Bs + wave * 512;

    const u16* Ab = ctx + (size_t)(mb * 128) * 1024;
    const u16* Bb = Wob + (size_t)(nb * 128) * 1024;

    const int swz = l15 & 7;

    f32x4 acc[4][4] = {};

    for (int k0 = 0; k0 < 1024; k0 += 64) {
        __syncthreads();
#pragma unroll
        for (int c = 0; c < 4; ++c) {
            size_t so = (size_t)(c * 32 + srow) * 1024 + k0 + scol;
            gld16(ldsA + c * 2048, Ab + so);
            gld16(ldsB + c * 2048, Bb + so);
        }
        __syncthreads();

#pragma unroll
        for (int ks = 0; ks < 2; ++ks) {
            short8 af[4], bf[4];
            const int ck = ((ks * 4 + quad) ^ swz) * 8;
#pragma unroll
            for (int mt = 0; mt < 4; ++mt)
                af[mt] = *(const short8*)(As + (wm + mt * 16 + l15) * 64 + ck);
#pragma unroll
            for (int nt = 0; nt < 4; ++nt)
                bf[nt] = *(const short8*)(Bs + (wn + nt * 16 + l15) * 64 + ck);
#pragma unroll
            for (int mt = 0; mt < 4; ++mt)
#pragma unroll
                for (int nt = 0; nt < 4; ++nt)
                    acc[mt][nt] = MFMA16(af[mt], bf[nt], acc[mt][nt]);
        }
    }

#pragma unroll
    for (int nt = 0; nt < 4; ++nt) {
        int col = nb * 128 + wn + nt * 16 + l15;
        float bv = bo[col];
#pragma unroll
        for (int mt = 0; mt < 4; ++mt)
#pragma unroll
            for (int r = 0; r < 4; ++r) {
                int row = mb * 128 + wm + mt * 16 + quad * 4 + r;
                out[(size_t)row * 1024 + col] = acc[mt][nt][r] + bv;
            }
    }
}

// ---------------------------------------------------------------------------
extern "C" void kernel_launch(void* const* d_in, const int* in_sizes, int n_in,
                              void* d_out, int out_size, void* d_ws, size_t ws_size,
                              hipStream_t stream)
{
    const float* X  = (const float*)d_in[0];
    const float* Wq = (const float*)d_in[1];
    const float* bq = (const float*)d_in[2];
    const float* Wk = (const float*)d_in[3];
    const float* bk = (const float*)d_in[4];
    const float* Wv = (const float*)d_in[5];
    const float* bv = (const float*)d_in[6];
    const float* Wo = (const float*)d_in[7];
    const float* bo = (const float*)d_in[8];

    const size_t M8 = 8388608;
    u16* q_att = (u16*)d_ws;
    u16* k_att = q_att + M8;
    u16* v_t   = k_att + M8;
    u16* Xb    = v_t   + M8;            // Xb dead after qkv -> ctx aliases it
    u16* ctx   = Xb;
    u16* Wcat  = Xb + M8;
    u16* Wob   = Wcat + 3 * 1048576;

    convert<<<dim3(3072), 256, 0, stream>>>(X, Wq, Wk, Wv, Wo, Xb, Wcat, Wob);
    qkv_gemm9<<<dim3(24, 64), 256, 0, stream>>>(Xb, Wcat, bq, bk, bv,
                                                q_att, k_att, v_t);
    attn5<<<dim3(64, 8), 256, 0, stream>>>(q_att, k_att, v_t, ctx);
    out_gemm9<<<dim3(8, 64), 256, 0, stream>>>(ctx, Wob, bo, (float*)d_out);
}